// Round 6
// baseline (27566.479 us; speedup 1.0000x reference)
//
#include <hip/hip_runtime.h>
#include <hip/hip_bf16.h>

// ---------------- problem constants ----------------
#define NPG   2000
#define BSZ   32
#define NTOT  64000
#define TDIM  256
#define HD    128
#define G4    512
#define MB    16
#define BPG   125
#define NBLK  4000

typedef float  f32x4 __attribute__((ext_vector_type(4)));
typedef short  s16x8 __attribute__((ext_vector_type(8)));
typedef unsigned int u32x2 __attribute__((ext_vector_type(2)));
typedef unsigned short u16;

__device__ __forceinline__ u16 f2bf(float x) {   // round-nearest-even
    unsigned u = __float_as_uint(x);
    return (u16)((u + 0x7FFFu + ((u >> 16) & 1u)) >> 16);
}
__device__ __forceinline__ unsigned cvt_pk_bf16(float lo, float hi) {
    unsigned r;
    asm("v_cvt_pk_bf16_f32 %0, %1, %2" : "=v"(r) : "v"(lo), "v"(hi));
    return r;
}
__device__ __forceinline__ float sigm(float x) { return 1.0f / (1.0f + __expf(-x)); }
__device__ __forceinline__ float tanh_(float x) { return 1.0f - 2.0f / (__expf(2.0f * x) + 1.0f); }

// async global->LDS DMA, 4B per lane, lds dest = uniform base + lane*4
__device__ __forceinline__ void gload_lds4(const float* g, void* l) {
    __builtin_amdgcn_global_load_lds(
        (const __attribute__((address_space(1))) void*)g,
        (__attribute__((address_space(3))) void*)l, 4, 0, 0);
}

// ---- permutations (same as R5, verified) ----
// gate-col interleave: col' = h*4 + g       (orig gate col = g*128 + h)
// D = A(W) x B(h): lane (lrow,lk), acc[nt][r]: node=lrow, col'=(wave*4+nt)*16+lk*4+r
// h-state slot perm16: slot = w*16 + l*4 + n <-> physical h = w*16 + n*4 + l

// ---------------- ws layout (float offsets) ----------------
#define OFF_M2    0
#define OFF_SHE0  4096
#define OFF_XN    8192
#define OFF_S0    8200192
#define OFF_S1    12394496
#define OFF_AN    16588800

// ---------------- dynamic LDS map (bytes), total 71680 = 70 KiB ----------------
#define L_WD1      0                      // [64][256] u16 swizzled, perm16 k    (32 KiB)
#define L_H0(p)   (32768 + (p) * 4096)    // [16][128] u16 swizzled, dbuf        (8 KiB)
#define L_H1(p)   (40960 + (p) * 4096)
#define L_C1(p)   (49152 + (p) * 4096)
#define L_D1(p)   (57344 + (p) * 2048)    // [16][64] u16 swizzled, dbuf         (4 KiB)
#define L_WD2     (61440)                 // 128 x s16x8                          (2 KiB)
#define L_S0(p)   (63488 + (p) * 2048)    // 512 f32, dbuf                        (4 KiB)
#define L_S1(p)   (67584 + (p) * 2048)
#define LDS_BYTES  71680

// ============== precompute: M2[j][col] = sum_h W_enc[h][j] * W_ih0[col][h] ==============
__global__ void k_m2(const float* __restrict__ Wenc, const float* __restrict__ Wih,
                     float* __restrict__ M2) {
    int col = threadIdx.x;  // 512
    float acc[6];
#pragma unroll
    for (int j = 0; j < 6; j++) acc[j] = 0.f;
    for (int h = 0; h < 128; h++) {
        float wv = Wih[col * 128 + h];
#pragma unroll
        for (int j = 0; j < 6; j++) acc[j] += Wenc[h * 137 + j] * wv;
    }
#pragma unroll
    for (int j = 0; j < 6; j++) M2[j * 512 + col] = acc[j];
}

// ============== precompute: anode[blk][node r][col'] (gate-col permuted) ==============
__global__ void k_anode(const float* __restrict__ node, const float* __restrict__ M2,
                        float* __restrict__ anode) {
    int blk = blockIdx.x;
    int col = threadIdx.x;  // 512 (orig col = g*128+h)
    float m[6];
#pragma unroll
    for (int j = 0; j < 6; j++) m[j] = M2[j * 512 + col];
    int colp = (col & 127) * 4 + (col >> 7);       // col' = h*4 + g
    float* dst = anode + (size_t)blk * 8192 + colp;
#pragma unroll
    for (int r = 0; r < 16; r++) {
        const float* np = node + (size_t)(blk * MB + r) * 6;
        float a = 0.f;
#pragma unroll
        for (int j = 0; j < 6; j++) a += np[j] * m[j];
        dst[r * 512] = a;
    }
}

// ============== precompute: xn[n][h] = sum_j node[n][j] * W_enc[h][j] ==============
__global__ void k_xn(const float* __restrict__ node, const float* __restrict__ Wenc,
                     float* __restrict__ xn) {
    int blk = blockIdx.x;             // 4000
    int h = threadIdx.x & 127;
    int rr = threadIdx.x >> 7;        // 0..3
#pragma unroll
    for (int i = 0; i < 4; i++) {
        int r = rr + i * 4;
        int n = blk * MB + r;
        float a = 0.f;
#pragma unroll
        for (int j = 0; j < 6; j++) a += node[(size_t)n * 6 + j] * Wenc[h * 137 + j];
        xn[(size_t)n * 128 + h] = a;
    }
}

// ============== precompute: shared per-(b,t) terms S0, S1 (col' order), shE0 ==============
__global__ void k_shared(const float* __restrict__ lat, const float* __restrict__ gms,
                         const float* __restrict__ Wenc, const float* __restrict__ benc,
                         const float* __restrict__ Wih, const float* __restrict__ bih,
                         const float* __restrict__ bhh,
                         float* __restrict__ S0, float* __restrict__ S1,
                         float* __restrict__ shE0) {
    int bt = blockIdx.x;             // 8192
    int b = bt >> 8, tt = bt & 255;
    __shared__ float she[128];
    int t = threadIdx.x;             // 256
    const float* latp = lat + (size_t)(b * 256 + tt) * 128;
    const float* gp = gms + (size_t)(b * 256 + tt) * 3;
    float g0 = gp[0], g1 = gp[1], g2 = gp[2];
    if (t < 128) {
        float a = benc[t];
        const float* we = Wenc + t * 137;
        for (int i = 0; i < 128; i++) a += latp[i] * we[6 + i];
        a += g0 * we[134] + g1 * we[135] + g2 * we[136];
        she[t] = a;
        if (tt == 0) shE0[b * 128 + t] = a;
    }
    __syncthreads();
    for (int col = t; col < 512; col += 256) {
        float a = bih[col] + bhh[col];
        const float* wr = Wih + col * 128;
        for (int h = 0; h < 128; h++) a += she[h] * wr[h];
        int colp = (col & 127) * 4 + (col >> 7);   // col' = h*4 + g
        S0[(size_t)(b * 256 + tt) * 512 + colp] = a;
        const float* w1 = Wih + 65536 + col * 128;
        float s1 = bih[512 + col] + bhh[512 + col] + g0 * w1[125] + g1 * w1[126] + g2 * w1[127];
        S1[(size_t)(b * 256 + tt) * 512 + colp] = s1;
    }
}

// ============== one pipeline step: out(t-2) | dec(t-1) | l1(t) | l0(t+1) | barrier ==============
template<int P, int L1f, int L0f, int DECf, int OUTf, int DMAf, int S0C>
__device__ __forceinline__ void step(
    int t, char* lds, int wave, int lane, int lrow, int lk,
    const s16x8 (&wb0)[4][4], const s16x8 (&wb1)[4][4], const s16x8 (&wb2)[4][4],
    const f32x4 (&anr)[4], float (&c0r)[4], float (&c1r)[4],
    const int (&rdA2)[2], const int (&wdA2)[2], const int (&d1Rd)[2],
    int hwByte, int sRd, int d1wByte,
    const f32x4 bd1i, const f32x4 bd2i,
    const float*& s1dma, const float*& s0dma,
    float* outp)
{
    constexpr int Q = 1 - P;
    // ---- issue next-iter S DMAs (in flight across the whole body) ----
    if (DMAf) {
        gload_lds4(s1dma, lds + L_S1(Q) + wave * 256);
        const float* s0src = S0C ? (s0dma - 512) : s0dma;
        gload_lds4(s0src, lds + L_S0(P) + wave * 256);
        s1dma += 512; s0dma += 512;
    }
    // ---- shared fragment loads (h0 used by l1+l0; h1 used by l1+dec) ----
    s16x8 a0[4], a1[4];
    if (L1f || L0f) {
        const char* h0 = lds + L_H0(P);
        a0[0] = *(const s16x8*)(h0 + rdA2[0]);
        a0[1] = *(const s16x8*)(h0 + rdA2[1]);
        a0[2] = *(const s16x8*)(h0 + rdA2[0] + 128);
        a0[3] = *(const s16x8*)(h0 + rdA2[1] + 128);
    }
    if (L1f || DECf) {
        const char* h1 = lds + L_H1(Q);
        a1[0] = *(const s16x8*)(h1 + rdA2[0]);
        a1[1] = *(const s16x8*)(h1 + rdA2[1]);
        a1[2] = *(const s16x8*)(h1 + rdA2[0] + 128);
        a1[3] = *(const s16x8*)(h1 + rdA2[1] + 128);
    }
    // ---- out(t-2): wave 4 ----
    if (OUTf) if (wave == 4) {
        const char* d1d = lds + L_D1(P);
        s16x8 bf0 = *(const s16x8*)(d1d + d1Rd[0]);
        s16x8 bf1 = *(const s16x8*)(d1d + d1Rd[1]);
        s16x8 w0 = *(const s16x8*)(lds + L_WD2 + lane * 16);
        s16x8 w1 = *(const s16x8*)(lds + L_WD2 + 1024 + lane * 16);
        f32x4 accO = bd2i;
        accO = __builtin_amdgcn_mfma_f32_16x16x32_bf16(w0, bf0, accO, 0, 0, 0);
        accO = __builtin_amdgcn_mfma_f32_16x16x32_bf16(w1, bf1, accO, 0, 0, 0);
        if (lk == 0) {
            float* op = outp + (size_t)lrow * (TDIM * 3) + (t - 2) * 3;
            op[0] = accO[0]; op[1] = accO[1]; op[2] = accO[2];
        }
    }
    // ---- layer1(t): gates = W_ih1z x h0(t) + W_hh1 x h1(t-1) + S1[t] ----
    if (L1f) {
        f32x4 acc[4];
        _Pragma("unroll")
        for (int nt = 0; nt < 4; nt++) acc[nt] = f32x4{0.f, 0.f, 0.f, 0.f};
        _Pragma("unroll")
        for (int kt = 0; kt < 4; kt++) {
            _Pragma("unroll")
            for (int nt = 0; nt < 4; nt++)
                acc[nt] = __builtin_amdgcn_mfma_f32_16x16x32_bf16(wb1[nt][kt], a0[kt], acc[nt], 0, 0, 0);
            _Pragma("unroll")
            for (int nt = 0; nt < 4; nt++)
                acc[nt] = __builtin_amdgcn_mfma_f32_16x16x32_bf16(wb2[nt][kt], a1[kt], acc[nt], 0, 0, 0);
        }
        float hf[4], cf[4];
        const char* s1p = lds + L_S1(P) + sRd;
        _Pragma("unroll")
        for (int nt = 0; nt < 4; nt++) {
            f32x4 sv = *(const f32x4*)(s1p + nt * 64);
            float iv = sigm(acc[nt][0] + sv[0]);
            float fv = sigm(acc[nt][1] + sv[1]);
            float gv = tanh_(acc[nt][2] + sv[2]);
            float ov = sigm(acc[nt][3] + sv[3]);
            float c = fv * c1r[nt] + iv * gv;
            c1r[nt] = c; cf[nt] = c; hf[nt] = ov * tanh_(c);
        }
        u32x2 hv, cv;
        hv[0] = cvt_pk_bf16(hf[0], hf[1]); hv[1] = cvt_pk_bf16(hf[2], hf[3]);
        cv[0] = cvt_pk_bf16(cf[0], cf[1]); cv[1] = cvt_pk_bf16(cf[2], cf[3]);
        *(u32x2*)(lds + L_H1(P) + hwByte) = hv;
        *(u32x2*)(lds + L_C1(P) + hwByte) = cv;
    }
    // ---- layer0(t+1): gates = W_hh0 x h0(t) + anode + S0[t+1] ----
    if (L0f) {
        f32x4 acc[4];
        _Pragma("unroll")
        for (int nt = 0; nt < 4; nt++) acc[nt] = f32x4{0.f, 0.f, 0.f, 0.f};
        _Pragma("unroll")
        for (int kt = 0; kt < 4; kt++) {
            _Pragma("unroll")
            for (int nt = 0; nt < 4; nt++)
                acc[nt] = __builtin_amdgcn_mfma_f32_16x16x32_bf16(wb0[nt][kt], a0[kt], acc[nt], 0, 0, 0);
        }
        float hf[4];
        const char* s0p = lds + L_S0(Q) + sRd;
        _Pragma("unroll")
        for (int nt = 0; nt < 4; nt++) {
            f32x4 sv = *(const f32x4*)(s0p + nt * 64);
            float iv = sigm(acc[nt][0] + anr[nt][0] + sv[0]);
            float fv = sigm(acc[nt][1] + anr[nt][1] + sv[1]);
            float gv = tanh_(acc[nt][2] + anr[nt][2] + sv[2]);
            float ov = sigm(acc[nt][3] + anr[nt][3] + sv[3]);
            float c = fv * c0r[nt] + iv * gv;
            c0r[nt] = c;
            hf[nt] = ov * tanh_(c);
        }
        u32x2 hv;
        hv[0] = cvt_pk_bf16(hf[0], hf[1]); hv[1] = cvt_pk_bf16(hf[2], hf[3]);
        *(u32x2*)(lds + L_H0(Q) + hwByte) = hv;
    }
    // ---- decoder(t-1): d1 = relu(Wd1 x [h1|c1] + bd1) on waves 0-3 (h1 frags = a1) ----
    if (DECf) if (wave < 4) {
        const char* c1d = lds + L_C1(Q);
        s16x8 cfr[4];
        cfr[0] = *(const s16x8*)(c1d + rdA2[0]);
        cfr[1] = *(const s16x8*)(c1d + rdA2[1]);
        cfr[2] = *(const s16x8*)(c1d + rdA2[0] + 128);
        cfr[3] = *(const s16x8*)(c1d + rdA2[1] + 128);
        const char* wd = lds + L_WD1;
        f32x4 acc2 = { 0.f, 0.f, 0.f, 0.f };
        _Pragma("unroll")
        for (int kt = 0; kt < 4; kt++) {
            s16x8 a = *(const s16x8*)(wd + wdA2[kt & 1] + (kt >> 1) * 128);
            acc2 = __builtin_amdgcn_mfma_f32_16x16x32_bf16(a, a1[kt], acc2, 0, 0, 0);
        }
        _Pragma("unroll")
        for (int kt = 0; kt < 4; kt++) {
            s16x8 a = *(const s16x8*)(wd + wdA2[kt & 1] + (kt >> 1) * 128 + 256);
            acc2 = __builtin_amdgcn_mfma_f32_16x16x32_bf16(a, cfr[kt], acc2, 0, 0, 0);
        }
        float d0 = acc2[0] + bd1i[0]; d0 = d0 > 0.f ? d0 : 0.f;
        float d1 = acc2[1] + bd1i[1]; d1 = d1 > 0.f ? d1 : 0.f;
        float d2 = acc2[2] + bd1i[2]; d2 = d2 > 0.f ? d2 : 0.f;
        float d3 = acc2[3] + bd1i[3]; d3 = d3 > 0.f ? d3 : 0.f;
        u32x2 dv;
        dv[0] = cvt_pk_bf16(d0, d1); dv[1] = cvt_pk_bf16(d2, d3);
        *(u32x2*)(lds + L_D1(Q) + d1wByte) = dv;
    }
    __syncthreads();
}

// ============== main fused kernel: peeled edges + 2x-unrolled steady state ==============
__global__ __launch_bounds__(512, 2) void k_main(
    const float* __restrict__ Wih, const float* __restrict__ Whh,
    const float* __restrict__ Wd1, const float* __restrict__ bd1,
    const float* __restrict__ Wd2, const float* __restrict__ bd2,
    const float* __restrict__ anode, const float* __restrict__ S0,
    const float* __restrict__ S1, const float* __restrict__ xn,
    const float* __restrict__ shE0, float* __restrict__ out) {
    extern __shared__ char lds[];

    const int tid = threadIdx.x;
    const int wave = tid >> 6, lane = tid & 63;
    const int lrow = lane & 15, lk = lane >> 4;
    const int blk = blockIdx.x;
    const int b = blk / BPG;
    const int nodeBase = blk * MB;

    // ---- persistent weight A-fragments (bf16), rows = col', perm16 k ----
    s16x8 wb0[4][4], wb1[4][4], wb2[4][4];
#pragma unroll
    for (int nt = 0; nt < 4; nt++) {
        const int hcol = wave * 16 + nt * 4 + (lrow >> 2);
        const int colI = (lrow & 3) * 128 + hcol;
#pragma unroll
        for (int kt = 0; kt < 4; kt++) {
            s16x8 v0, v1, v2;
#pragma unroll
            for (int j = 0; j < 8; j++) {
                int kp = kt * 32 + lk * 8 + j;                      // k' slot
                int k = (kp & ~15) | ((kp & 3) << 2) | ((kp >> 2) & 3);  // physical h
                v0[j] = (short)f2bf(Whh[colI * 128 + k]);
                float w1 = (k >= 125) ? 0.0f : Wih[65536 + colI * 128 + k];
                v1[j] = (short)f2bf(w1);
                v2[j] = (short)f2bf(Whh[65536 + colI * 128 + k]);
            }
            wb0[nt][kt] = v0; wb1[nt][kt] = v1; wb2[nt][kt] = v2;
        }
    }

    // ---- stage W_d1 -> LDS bf16 swizzled, perm16 k within each 128-half ----
    {
        int row = tid >> 3, k0 = (tid & 7) * 32;
#pragma unroll
        for (int i = 0; i < 4; i++) {
            s16x8 v;
#pragma unroll
            for (int j = 0; j < 8; j++) {
                int kp = k0 + i * 8 + j;          // 0..255
                int kin = kp & 127;
                int k = (kin & ~15) | ((kin & 3) << 2) | ((kin >> 2) & 3);
                v[j] = (short)f2bf(Wd1[row * 256 + (kp & 128) + k]);
            }
            int byte = (row * 512 + (k0 + i * 8) * 2) ^ ((row & 7) << 4);
            *(s16x8*)(lds + L_WD1 + byte) = v;
        }
    }
    // ---- stage Wd2 A-fragments ----
    if (tid < 128) {
        int kt = tid >> 6, ln = tid & 63;
        int rw = ln & 15, ks = kt * 32 + (ln >> 4) * 8;
        s16x8 v;
#pragma unroll
        for (int j = 0; j < 8; j++)
            v[j] = (rw < 3) ? (short)f2bf(Wd2[rw * 64 + ks + j]) : (short)0;
        *(s16x8*)(lds + L_WD2 + tid * 16) = v;
    }
    // ---- anode -> 16 registers (loop-invariant addend) ----
    f32x4 anr[4];
    {
        const float* ap = anode + (size_t)blk * 8192 + lrow * 512 + wave * 64 + lk * 4;
#pragma unroll
        for (int nt = 0; nt < 4; nt++) anr[nt] = *(const f32x4*)(ap + nt * 16);
    }
    // ---- per-lane h-state write offset ----
    const int hwByte = (lrow * 256 + wave * 32 + lk * 8) ^ ((lrow & 7) << 4);
    // ---- init state: H0=C0=H1=C1 = x0 -> parity-1 buffers ----
    float c0r[4], c1r[4];
    {
        float x0[4];
#pragma unroll
        for (int nt = 0; nt < 4; nt++) {
            int h = wave * 16 + nt * 4 + lk;
            x0[nt] = xn[(size_t)(nodeBase + lrow) * 128 + h] + shE0[b * 128 + h];
            c0r[nt] = x0[nt]; c1r[nt] = x0[nt];
        }
        u32x2 hv;
        hv[0] = cvt_pk_bf16(x0[0], x0[1]); hv[1] = cvt_pk_bf16(x0[2], x0[3]);
        *(u32x2*)(lds + L_H0(1) + hwByte) = hv;
        *(u32x2*)(lds + L_H1(1) + hwByte) = hv;
    }
    // ---- fragment/addend read offsets ----
    int rdA2[2], wdA2[2], d1Rd[2];
    const int colD = (wave & 3) * 16 + lrow;
#pragma unroll
    for (int j = 0; j < 2; j++) {
        rdA2[j] = (lrow * 256 + j * 64 + lk * 16) ^ ((lrow & 7) << 4);
        wdA2[j] = (colD * 512 + j * 64 + lk * 16) ^ ((colD & 7) << 4);
        d1Rd[j] = (lrow * 128 + j * 64 + lk * 16) ^ ((lrow & 7) << 4);
    }
    const int d1wByte = (lrow * 128 + wave * 32 + lk * 8) ^ ((lrow & 7) << 4);
    const int sRd = wave * 256 + lk * 16;
    const f32x4 bd1i = *(const f32x4*)(bd1 + (wave & 3) * 16 + lk * 4);
    f32x4 bd2i;
#pragma unroll
    for (int r = 0; r < 4; r++)
        bd2i[r] = (lk == 0 && r < 3) ? bd2[r] : 0.f;

    const float* s1dma = S1 + (size_t)b * 256 * 512 + wave * 64 + lane;       // -> s1[t+1]
    const float* s0dma = S0 + (size_t)b * 256 * 512 + 512 + wave * 64 + lane; // -> s0[t+2]
    // prologue: stage s0[0] -> parity 0 (consumed by l0 phase at t=-1)
    gload_lds4(S0 + (size_t)b * 256 * 512 + wave * 64 + lane, lds + L_S0(0) + wave * 256);
    __syncthreads();   // drains DMA + staging

    float* outp = out + (size_t)nodeBase * (TDIM * 3);

#define ARGS lds, wave, lane, lrow, lk, wb0, wb1, wb2, anr, c0r, c1r, \
             rdA2, wdA2, d1Rd, hwByte, sRd, d1wByte, bd1i, bd2i, s1dma, s0dma, outp

    //            P  L1 L0 DEC OUT DMA S0C
    step<1, 0, 1, 0, 0, 1, 0>(-1, ARGS);
    step<0, 1, 1, 0, 0, 1, 0>(0, ARGS);
    step<1, 1, 1, 1, 0, 1, 0>(1, ARGS);
#pragma unroll 1
    for (int t = 2; t < 254; t += 2) {
        step<0, 1, 1, 1, 1, 1, 0>(t, ARGS);
        step<1, 1, 1, 1, 1, 1, 0>(t + 1, ARGS);
    }
    step<0, 1, 1, 1, 1, 1, 1>(254, ARGS);   // tn0 clamps to 255
    step<1, 1, 0, 1, 1, 0, 0>(255, ARGS);
    step<0, 0, 0, 1, 1, 0, 0>(256, ARGS);
    step<1, 0, 0, 1, 1, 0, 0>(257, ARGS);
#undef ARGS
}

extern "C" void kernel_launch(void* const* d_in, const int* in_sizes, int n_in,
                              void* d_out, int out_size, void* d_ws, size_t ws_size,
                              hipStream_t stream) {
    const float* node = (const float*)d_in[0];
    // d_in[1] = ptr (int32) — layout is fixed arange*2000, handled analytically
    const float* lat  = (const float*)d_in[2];
    const float* gms  = (const float*)d_in[3];
    const float* Wenc = (const float*)d_in[4];
    const float* benc = (const float*)d_in[5];
    const float* Wih  = (const float*)d_in[6];
    const float* Whh  = (const float*)d_in[7];
    const float* bih  = (const float*)d_in[8];
    const float* bhh  = (const float*)d_in[9];
    const float* Wd1  = (const float*)d_in[10];
    const float* bd1  = (const float*)d_in[11];
    const float* Wd2  = (const float*)d_in[12];
    const float* bd2  = (const float*)d_in[13];

    float* ws    = (float*)d_ws;
    float* M2    = ws + OFF_M2;
    float* shE0  = ws + OFF_SHE0;
    float* xn    = ws + OFF_XN;
    float* S0    = ws + OFF_S0;
    float* S1    = ws + OFF_S1;
    float* anode = ws + OFF_AN;

    k_m2<<<1, 512, 0, stream>>>(Wenc, Wih, M2);
    k_anode<<<NBLK, 512, 0, stream>>>(node, M2, anode);
    k_xn<<<NBLK, 512, 0, stream>>>(node, Wenc, xn);
    k_shared<<<BSZ * TDIM, 256, 0, stream>>>(lat, gms, Wenc, benc, Wih, bih, bhh, S0, S1, shE0);
    k_main<<<NBLK, 512, LDS_BYTES, stream>>>(Wih, Whh, Wd1, bd1, Wd2, bd2,
                                             anode, S0, S1, xn, shE0, (float*)d_out);
}